// Round 4
// baseline (556.587 us; speedup 1.0000x reference)
//
#include <hip/hip_runtime.h>

// ---------- types ----------
typedef __attribute__((ext_vector_type(8))) short short8;   // 8 bf16 (4 VGPRs)
typedef __attribute__((ext_vector_type(4))) float f32x4;

// ---------- problem constants ----------
#define NB     32
#define PLANE  12544        // 112*112
#define XTOT   51380224     // 32*128*112*112
#define NGX    1427229      // ceil(XTOT/36)
// workspace layout (bytes)
#define XPAD_BYTES 106463232ULL   // 32*114*114*128 * 2
#define WG_OFF     XPAD_BYTES
#define SE_OFF     (XPAD_BYTES + 294912ULL)

__device__ __forceinline__ void gld_lds16(const void* g, void* l) {
  __builtin_amdgcn_global_load_lds(
      (__attribute__((address_space(1))) unsigned int*)g,
      (__attribute__((address_space(3))) unsigned int*)l, 16, 0, 0);
}

__device__ __forceinline__ float qmax4(float4 v, float m) {
  m = fmaxf(m, fabsf(v.x)); m = fmaxf(m, fabsf(v.y));
  m = fmaxf(m, fabsf(v.z)); m = fmaxf(m, fabsf(v.w));
  return m;
}

__device__ __forceinline__ int bfp_exp(float m) {
  int e = 0;
  if (m > 0.f) {
    e = (int)((__float_as_uint(m) >> 23) & 255) - 127;
    if (e < -100) e = -100;
  }
  return e;
}

// q = clip(rint(v * 2^(7-e)), -128, 127) * 2^(e-7); exactly bf16-representable
__device__ __forceinline__ unsigned int bfp_q(float v, float inv, float st) {
  float qq = fminf(fmaxf(rintf(v * inv), -128.f), 127.f) * st;
  return __float_as_uint(qq) >> 16;
}

// ---------- kernel 1: per-group exponent of x (coalesced + LDS reduce) ----------
// block: 256 threads, 1008 float4 = 112 groups per block (36 elems = 9 float4, aligned)
__global__ __launch_bounds__(256) void quant_step_x(const float* __restrict__ x,
                                                    signed char* __restrict__ se) {
  __shared__ float red[1008];
  const long long base4 = (long long)blockIdx.x * 1008;
  const int t = threadIdx.x;
#pragma unroll
  for (int i = 0; i < 4; ++i) {
    int idx = t + i * 256;
    if (idx < 1008) {
      long long f4 = base4 + idx;
      float m = 0.f;
      if (f4 * 4 < XTOT) {                     // XTOT is a multiple of 4
        float4 v = *(const float4*)(x + f4 * 4);
        m = qmax4(v, 0.f);
      }
      red[idx] = m;
    }
  }
  __syncthreads();
  if (t < 112) {
    long long g = (long long)blockIdx.x * 112 + t;
    if (g < NGX) {
      float m = red[t * 9];
#pragma unroll
      for (int k = 1; k < 9; ++k) m = fmaxf(m, red[t * 9 + k]);
      se[g] = (signed char)bfp_exp(m);
    }
  }
}

// ---------- kernel 2: quantize + reorder weights to [step=rs*4+cib][co][ci32] bf16 ----------
__global__ __launch_bounds__(64) void quant_w_kernel(const float* __restrict__ w,
                                                     unsigned short* __restrict__ wg) {
  int g = blockIdx.x * 64 + threadIdx.x;   // 4096 groups, exact
  if (g >= 4096) return;
  const float4* p4 = (const float4*)(w + g * 36);
  float4 v[9];
  float m = 0.f;
#pragma unroll
  for (int j = 0; j < 9; ++j) { v[j] = p4[j]; m = qmax4(v[j], m); }
  int e = bfp_exp(m);
  float inv = __uint_as_float((unsigned)(134 - e) << 23);  // 2^(7-e)
  float st  = __uint_as_float((unsigned)(120 + e) << 23);  // 2^(e-7)
#pragma unroll
  for (int j = 0; j < 9; ++j) {
    float tmp[4] = {v[j].x, v[j].y, v[j].z, v[j].w};
#pragma unroll
    for (int k = 0; k < 4; ++k) {
      int f = g * 36 + j * 4 + k;   // flat index in [co][ci][kh][kw]
      int co = f / 1152;
      int rem = f % 1152;
      int ci = rem / 9;
      int rs = rem % 9;
      int stp = rs * 4 + (ci >> 5);
      wg[(stp * 128 + co) * 32 + (ci & 31)] = (unsigned short)bfp_q(tmp[k], inv, st);
    }
  }
}

// ---------- kernel 3: zero halo of padded NHWC x ----------
__global__ __launch_bounds__(256) void border_zero(unsigned short* __restrict__ xpad) {
  int tid = blockIdx.x * 256 + threadIdx.x;
  if (tid >= NB * 452 * 16) return;
  int b = tid / (452 * 16);
  int r = tid % (452 * 16);
  int pos = r >> 4, cc = r & 15;
  int hp, wp;
  if (pos < 114)      { hp = 0;             wp = pos; }
  else if (pos < 228) { hp = 113;           wp = pos - 114; }
  else if (pos < 340) { hp = pos - 228 + 1; wp = 0; }
  else                { hp = pos - 340 + 1; wp = 113; }
  float4 z = make_float4(0.f, 0.f, 0.f, 0.f);
  *(float4*)&xpad[((size_t)((b * 114 + hp) * 114 + wp)) * 128 + cc * 8] = z;
}

// ---------- kernel 4: quantize x + transpose NCHW -> padded NHWC bf16 ----------
// tile: 64 p x 128 ci. Scalar-coalesced reads (64 lanes = 256B contiguous),
// 8B-slot XOR-swizzled LDS transpose, 16B-contiguous NHWC writes.
__global__ __launch_bounds__(256) void quant_pad_x(const float* __restrict__ x,
                                                   const signed char* __restrict__ se,
                                                   unsigned short* __restrict__ xpad) {
  __shared__ unsigned short tile[64 * 128];   // [p][8B-slot, swizzled]
  const int t = threadIdx.x;
  const int b = blockIdx.y;
  const int p0 = blockIdx.x * 64;
  const int pl = t & 63;
  const int p = p0 + pl;
  const int cq = (t >> 6) * 4;                 // ci quad base per wave
  const unsigned planebase = (unsigned)(b * 128) * PLANE + p;

#pragma unroll
  for (int i = 0; i < 8; ++i) {
    int ci0 = cq + 16 * i;
    unsigned q[4];
#pragma unroll
    for (int j = 0; j < 4; ++j) {
      unsigned f = planebase + (unsigned)(ci0 + j) * PLANE;
      float v = x[f];
      int e = se[f / 36u];
      float inv = __uint_as_float((unsigned)(134 - e) << 23);
      float st  = __uint_as_float((unsigned)(120 + e) << 23);
      q[j] = bfp_q(v, inv, st);
    }
    int phys = (ci0 >> 2) ^ (pl & 31);
    uint2 pk;
    pk.x = q[0] | (q[1] << 16);
    pk.y = q[2] | (q[3] << 16);
    *(uint2*)&tile[pl * 128 + phys * 4] = pk;
  }
  __syncthreads();
#pragma unroll
  for (int j = 0; j < 4; ++j) {
    int pl2 = (t >> 4) + 16 * j;
    int c = t & 15;                      // 16 chunks x 8 ushorts = 128 ci
    int m = pl2 & 31;
    int ps = (2 * c) ^ m;                // phys slot of logical quad 2c
    uint4 v = *(uint4*)&tile[pl2 * 128 + (ps & ~1) * 4];
    uint4 o;
    if (m & 1) { o.x = v.z; o.y = v.w; o.z = v.x; o.w = v.y; }
    else       { o = v; }
    int p2 = p0 + pl2;
    int h = p2 / 112, w = p2 % 112;
    size_t dst = ((size_t)((b * 114 + h + 1) * 114) + (w + 1)) * 128 + c * 8;  // 8 ushorts per chunk!
    *(uint4*)&xpad[dst] = o;
  }
}

// ---------- kernel 5: implicit-GEMM conv, bf16 MFMA, BK=64 ----------
// block = 256 (4 waves, 2x2), tile = 128 co x 128 p, 18 stages of (rs, ci64-half)
// LDS: A bytes [0,16384), B bytes [16384,32768)  -- 32 KB total
__global__ __launch_bounds__(256) void conv_mfma(const unsigned short* __restrict__ xpad,
                                                 const unsigned short* __restrict__ wg,
                                                 const float* __restrict__ bias,
                                                 float* __restrict__ out) {
  __shared__ unsigned short smem[16384];   // 32768 bytes
  char* smb = (char*)smem;
  const int t = threadIdx.x;
  const int lane = t & 63, wv = t >> 6;
  const int lane15 = lane & 15, quad = lane >> 4;
  const int wm = wv >> 1, wn = wv & 1;
  const int b = blockIdx.y;
  const int p0 = blockIdx.x * 128;

  // staging sources: slot idx = t + i*256 -> (row = idx>>3, phys chunk c = idx&7);
  // slot holds logical chunk cl = c ^ sw(row), sw = (row>>1)&7
  int a_src[4], b_src[4];
#pragma unroll
  for (int i = 0; i < 4; ++i) {
    int idx = t + i * 256;
    int row = idx >> 3;
    int c = idx & 7;
    int cl = c ^ ((row >> 1) & 7);
    a_src[i] = row * 32 + (cl >> 2) * 4096 + (cl & 3) * 8;  // elems into wg stage window
    int p = p0 + row;
    int h = p / 112, ww = p % 112;
    b_src[i] = ((b * 114 + h) * 114 + ww) * 128 + cl * 8;   // + bofs per stage
  }

  // fragment LDS byte offsets: row*128B + phys_chunk*16, phys = (kk*4+quad)^sw(row)
  int a_off[4][2], b_off[4][2];
#pragma unroll
  for (int f = 0; f < 4; ++f) {
#pragma unroll
    for (int kk = 0; kk < 2; ++kk) {
      int row = wm * 64 + f * 16 + lane15;
      a_off[f][kk] = row * 128 + (((kk * 4 + quad) ^ ((row >> 1) & 7)) * 16);
      int prow = wn * 64 + f * 16 + lane15;
      b_off[f][kk] = 16384 + prow * 128 + (((kk * 4 + quad) ^ ((prow >> 1) & 7)) * 16);
    }
  }

  f32x4 acc[4][4];
  f32x4 zero = {0.f, 0.f, 0.f, 0.f};
#pragma unroll
  for (int i = 0; i < 4; ++i)
#pragma unroll
    for (int j = 0; j < 4; ++j) acc[i][j] = zero;

  for (int stage = 0; stage < 18; ++stage) {
    int rs = stage >> 1, half = stage & 1;
    int r = rs / 3, s = rs - r * 3;
    int aofs = (rs * 4 + half * 2) * 4096;
    int bofs = (r * 114 + s) * 128 + half * 64;
    __syncthreads();
#pragma unroll
    for (int i = 0; i < 4; ++i) {
      gld_lds16(wg + aofs + a_src[i],   smb + t * 16 + i * 4096);
      gld_lds16(xpad + bofs + b_src[i], smb + 16384 + t * 16 + i * 4096);
    }
    __syncthreads();
#pragma unroll
    for (int kk = 0; kk < 2; ++kk) {
      short8 af[4], bf[4];
#pragma unroll
      for (int f = 0; f < 4; ++f) af[f] = *(const short8*)(smb + a_off[f][kk]);
#pragma unroll
      for (int f = 0; f < 4; ++f) bf[f] = *(const short8*)(smb + b_off[f][kk]);
#pragma unroll
      for (int i = 0; i < 4; ++i)
#pragma unroll
        for (int j = 0; j < 4; ++j)
          acc[i][j] = __builtin_amdgcn_mfma_f32_16x16x32_bf16(af[i], bf[j], acc[i][j], 0, 0, 0);
    }
  }

  // epilogue: C/D layout col=lane&15 (p), row=quad*4+reg (co); + bias
#pragma unroll
  for (int i = 0; i < 4; ++i)
#pragma unroll
    for (int j = 0; j < 4; ++j) {
      int p = p0 + wn * 64 + j * 16 + lane15;
#pragma unroll
      for (int rr = 0; rr < 4; ++rr) {
        int co = wm * 64 + i * 16 + quad * 4 + rr;
        out[(b * 128 + co) * PLANE + p] = acc[i][j][rr] + bias[co];
      }
    }
}

extern "C" void kernel_launch(void* const* d_in, const int* in_sizes, int n_in,
                              void* d_out, int out_size, void* d_ws, size_t ws_size,
                              hipStream_t stream) {
  const float* x    = (const float*)d_in[0];
  const float* w    = (const float*)d_in[1];
  const float* bias = (const float*)d_in[2];
  float* out = (float*)d_out;
  char* ws = (char*)d_ws;
  unsigned short* xpad = (unsigned short*)ws;
  unsigned short* wg   = (unsigned short*)(ws + WG_OFF);
  signed char*    se   = (signed char*)(ws + SE_OFF);

  quant_step_x<<<12744, 256, 0, stream>>>(x, se);        // 12744*112 >= NGX groups
  quant_w_kernel<<<64, 64, 0, stream>>>(w, wg);
  border_zero<<<904, 256, 0, stream>>>(xpad);
  quant_pad_x<<<dim3(196, 32), 256, 0, stream>>>(x, se, xpad);
  conv_mfma<<<dim3(98, 32), 256, 0, stream>>>(xpad, wg, bias, out);
}